// Round 7
// baseline (234.954 us; speedup 1.0000x reference)
//
#include <hip/hip_runtime.h>
#include <stdint.h>

typedef unsigned short ushort_t;
typedef __attribute__((ext_vector_type(8))) __bf16 bf16x8;
typedef __attribute__((ext_vector_type(4))) float floatx4;

__device__ __forceinline__ ushort_t f2bf(float f) {
    uint32_t u = __builtin_bit_cast(uint32_t, f);
    u += 0x7fffu + ((u >> 16) & 1u);
    return (ushort_t)(u >> 16);
}

// async 16B global->LDS (deposit at ldsbase + lane*16; ldsbase wave-uniform)
typedef __attribute__((address_space(1))) const void glb_void;
typedef __attribute__((address_space(3))) void lds_void;
__device__ __forceinline__ void gld16(const void* g, void* l) {
    __builtin_amdgcn_global_load_lds((glb_void*)g, (lds_void*)l, 16, 0, 0);
}

// Q pre-scale: dh^-0.5 * log2(e) so attention softmax runs in exp2 domain.
#define QSCALE 0.18033688011112042f

// ---------------- cast: fp32 -> bf16 ----------------
__global__ void cast_kernel(const float* __restrict__ x,
                            const float* __restrict__ Wq, const float* __restrict__ Wk,
                            const float* __restrict__ Wv, const float* __restrict__ Wp,
                            ushort_t* __restrict__ xb, ushort_t* __restrict__ Wqkvb,
                            ushort_t* __restrict__ Wpb)
{
    const int64_t NX = 4194304, NW = 1048576;
    int64_t i4 = ((int64_t)blockIdx.x * blockDim.x + threadIdx.x) * 4;
    const float* src; ushort_t* dst; int64_t off;
    if (i4 < NX)            { src = x;  dst = xb;          off = i4; }
    else if (i4 < NX+NW)    { src = Wq; dst = Wqkvb;       off = i4 - NX; }
    else if (i4 < NX+2*NW)  { src = Wk; dst = Wqkvb + NW;  off = i4 - NX - NW; }
    else if (i4 < NX+3*NW)  { src = Wv; dst = Wqkvb + 2*NW;off = i4 - NX - 2*NW; }
    else                    { src = Wp; dst = Wpb;         off = i4 - NX - 3*NW; }
    float4 v = *(const float4*)(src + off);
    ushort4 o;
    o.x = f2bf(v.x); o.y = f2bf(v.y); o.z = f2bf(v.z); o.w = f2bf(v.w);
    *(ushort4*)(dst + off) = o;
}

// ---------------- bf16 GEMM: D = A @ B^T  (global_load_lds staging) ----------------
// MODE 0 (BN_=128): scatter Q,K -> [bh][s][d] (Q pre-scaled), V -> [bh][d][s]
// MODE 1: fp32 out = D + bias
#define BM 128
#define BK 32

template<int BN_, int MODE>
__global__ __launch_bounds__(256, 3)
void gemm_bt(const ushort_t* __restrict__ A, const ushort_t* __restrict__ Bmat,
             int M, int N, int K,
             ushort_t* __restrict__ qb, ushort_t* __restrict__ kb, ushort_t* __restrict__ vtb,
             float* __restrict__ outf, const float* __restrict__ bias)
{
    constexpr int NB_B = BN_ * BK / 512;
    constexpr int NT   = BN_ / 32;
    constexpr int PER_W = (8 + NB_B) / 4;
    __shared__ ushort_t As[BM * BK];
    __shared__ ushort_t Bs[BN_ * BK];
    const int tid  = threadIdx.x;
    const int lane = tid & 63;
    const int wave = tid >> 6;
    const int m0 = blockIdx.x * BM;
    const int n0 = blockIdx.y * BN_;
    const int wrow = (wave >> 1) * 64;
    const int wcol = (wave & 1) * (BN_ / 2);
    const int q_ = lane >> 4;
    const int ml = lane & 15;

    floatx4 acc[4][NT];
    for (int i = 0; i < 4; i++) for (int j = 0; j < NT; j++) acc[i][j] = floatx4{0.f,0.f,0.f,0.f};

    const int row_l = lane >> 2;
    const int col_l = (lane & 3) * 8;
    const ushort_t* gptr[PER_W]; ushort_t* lptr[PER_W];
    for (int i = 0; i < PER_W; i++) {
        int id = wave * PER_W + i;
        if (id < 8) {
            gptr[i] = A + (int64_t)(m0 + id*16 + row_l) * K + col_l;
            lptr[i] = As + id * 512;
        } else {
            int j = id - 8;
            gptr[i] = Bmat + (int64_t)(n0 + j*16 + row_l) * K + col_l;
            lptr[i] = Bs + j * 512;
        }
    }

    for (int k0 = 0; k0 < K; k0 += BK) {
        __syncthreads();
        for (int i = 0; i < PER_W; i++) gld16(gptr[i] + k0, lptr[i]);
        __syncthreads();
        bf16x8 af[4], bf[NT];
        for (int mt = 0; mt < 4; mt++)
            af[mt] = *(const bf16x8*)(As + (wrow + mt*16 + ml) * BK + q_*8);
        for (int nt = 0; nt < NT; nt++)
            bf[nt] = *(const bf16x8*)(Bs + (wcol + nt*16 + ml) * BK + q_*8);
        for (int mt = 0; mt < 4; mt++)
            for (int nt = 0; nt < NT; nt++)
                acc[mt][nt] = __builtin_amdgcn_mfma_f32_16x16x32_bf16(af[mt], bf[nt], acc[mt][nt], 0, 0, 0);
    }

    if constexpr (MODE == 0) {
        for (int mt = 0; mt < 4; mt++) for (int nt = 0; nt < NT; nt++) {
            floatx4 v = acc[mt][nt];
            int col = n0 + wcol + nt*16 + ml;
            int which = col >> 10;
            int nn = col & 1023;
            int h = nn >> 6, d = nn & 63;
            if (which < 2) {
                ushort_t* dst = (which == 0) ? qb : kb;
                float sc = (which == 0) ? QSCALE : 1.0f;
                for (int r = 0; r < 4; r++) {
                    int rowg = m0 + wrow + mt*16 + q_*4 + r;
                    int b = rowg >> 11, s = rowg & 2047;
                    dst[(((int64_t)(b*16 + h) * 2048 + s) << 6) + d] = f2bf(v[r] * sc);
                }
            } else {
                int rowg0 = m0 + wrow + mt*16 + q_*4;
                int b = rowg0 >> 11, sbase = rowg0 & 2047;
                ushort4 o;
                o.x = f2bf(v[0]); o.y = f2bf(v[1]); o.z = f2bf(v[2]); o.w = f2bf(v[3]);
                *(ushort4*)(vtb + (((int64_t)(b*16 + h) * 64 + d) << 11) + sbase) = o;
            }
        }
    } else {
        for (int mt = 0; mt < 4; mt++) for (int nt = 0; nt < NT; nt++) {
            floatx4 v = acc[mt][nt];
            int col = n0 + wcol + nt*16 + ml;
            float bv = bias[col];
            for (int r = 0; r < 4; r++) {
                int rowg = m0 + wrow + mt*16 + q_*4 + r;
                outf[(int64_t)rowg * N + col] = v[r] + bv;
            }
        }
    }
}

// ---------------- fused masked flash attention: 1 wave / 32 q-rows, NO barriers ----
// K/V fragments gathered global->VGPR (L2-resident, XCD-pinned). LDS only for the
// wave-private P round-trip (stride 136 >= 128-key row!). No-max softmax.
__global__ __launch_bounds__(64)
void attn_kernel(const ushort_t* __restrict__ Q, const ushort_t* __restrict__ Kb,
                 const ushort_t* __restrict__ Vt, ushort_t* __restrict__ Out)
{
    __shared__ ushort_t Pl[2 * 16 * 136];  // 8.5KB, wave-private; row = 128 keys + pad

    int bi = blockIdx.x;                   // 2048 blocks
    int xcd = bi & 7;
    int sl  = bi >> 3;                     // 0..255
    int bh  = xcd + 8 * (sl & 3);
    int rest = sl >> 2;                    // 0..63
    int qv = 7 - (rest >> 3);              // heavy views first
    int qt = rest & 7;
    int b = bh >> 4, h = bh & 15;
    int lane = threadIdx.x & 63;
    int q_ = lane >> 4, ml = lane & 15;
    int s0 = qv*256 + qt*32;

    const ushort_t* Kbh = Kb + ((int64_t)bh << 17);
    const ushort_t* Vbh = Vt + ((int64_t)bh << 17);

    bf16x8 aq0[2], aq1[2];
    for (int qf = 0; qf < 2; qf++) {
        const ushort_t* Qp = Q + (((int64_t)bh*2048 + s0 + qf*16 + ml) << 6) + q_*8;
        aq0[qf] = *(const bf16x8*)(Qp);
        aq1[qf] = *(const bf16x8*)(Qp + 32);
    }

    floatx4 o_acc[2][4];
    for (int qf = 0; qf < 2; qf++) for (int i = 0; i < 4; i++) o_acc[qf][i] = floatx4{0.f,0.f,0.f,0.f};
    float lsum[2][4];
    for (int qf = 0; qf < 2; qf++) for (int r = 0; r < 4; r++) lsum[qf][r] = 0.f;

    int views[8]; int nviews;
    if      (qv == 0) { views[0] = 1; nviews = 1; }
    else if (qv == 1) { views[0] = 0; nviews = 1; }
    else { nviews = qv + 1; for (int i = 0; i < nviews; i++) views[i] = i; }

    for (int vi = 0; vi < nviews; vi++) {
        int kb0 = views[vi] * 256;
        for (int ck = 0; ck < 2; ck++) {
            int koff = kb0 + ck * 128;

            // ---- S = Q @ K^T over 128 keys; K frags straight from global (L2) ----
            floatx4 sc[2][8];
            for (int kt = 0; kt < 8; kt++) {
                const ushort_t* Kp = Kbh + (((int64_t)(koff + kt*16 + ml)) << 6) + q_*8;
                bf16x8 k0 = *(const bf16x8*)(Kp);
                bf16x8 k1 = *(const bf16x8*)(Kp + 32);
                for (int qf = 0; qf < 2; qf++) {
                    floatx4 cz = floatx4{0.f,0.f,0.f,0.f};
                    cz = __builtin_amdgcn_mfma_f32_16x16x32_bf16(aq0[qf], k0, cz, 0, 0, 0);
                    cz = __builtin_amdgcn_mfma_f32_16x16x32_bf16(aq1[qf], k1, cz, 0, 0, 0);
                    sc[qf][kt] = cz;
                }
            }

            // ---- p = exp2(s); partial l; P -> LDS ----
            for (int qf = 0; qf < 2; qf++)
                for (int kt = 0; kt < 8; kt++)
                    for (int r = 0; r < 4; r++) {
                        float p = __builtin_amdgcn_exp2f(sc[qf][kt][r]);
                        lsum[qf][r] += p;
                        Pl[qf*2176 + (q_*4 + r)*136 + kt*16 + ml] = f2bf(p);
                    }

            asm volatile("s_waitcnt lgkmcnt(0)" ::: "memory");  // wave-private P visible

            // ---- O += P @ V; V frags straight from global (L2) ----
            for (int g = 0; g < 4; g++) {
                bf16x8 ap[2];
                for (int qf = 0; qf < 2; qf++)
                    ap[qf] = *(const bf16x8*)(Pl + qf*2176 + ml*136 + g*32 + q_*8);
                for (int dt = 0; dt < 4; dt++) {
                    const ushort_t* Vp = Vbh + ((int64_t)(dt*16 + ml) << 11) + koff + g*32 + q_*8;
                    bf16x8 vv = *(const bf16x8*)(Vp);
                    for (int qf = 0; qf < 2; qf++)
                        o_acc[qf][dt] = __builtin_amdgcn_mfma_f32_16x16x32_bf16(ap[qf], vv, o_acc[qf][dt], 0, 0, 0);
                }
            }
            asm volatile("s_waitcnt lgkmcnt(0)" ::: "memory");  // P reads done before overwrite
        }
    }

    // final l reduction across the 16 lanes of each row group
    for (int off = 1; off < 16; off <<= 1)
        for (int qf = 0; qf < 2; qf++)
            for (int r = 0; r < 4; r++)
                lsum[qf][r] += __shfl_xor(lsum[qf][r], off);

    // epilogue: Out[b][s][h*64+d] = o/l (bf16)
    for (int qf = 0; qf < 2; qf++)
        for (int dt = 0; dt < 4; dt++)
            for (int r = 0; r < 4; r++) {
                float v = o_acc[qf][dt][r] / lsum[qf][r];
                int sr = s0 + qf*16 + q_*4 + r;
                Out[((int64_t)b*2048 + sr) * 1024 + h*64 + dt*16 + ml] = f2bf(v);
            }
}

extern "C" void kernel_launch(void* const* d_in, const int* in_sizes, int n_in,
                              void* d_out, int out_size, void* d_ws, size_t ws_size,
                              hipStream_t stream) {
    const float* x  = (const float*)d_in[0];
    const float* Wq = (const float*)d_in[1];
    const float* Wk = (const float*)d_in[2];
    const float* Wv = (const float*)d_in[3];
    const float* Wp = (const float*)d_in[4];
    const float* bp = (const float*)d_in[5];
    float* out = (float*)d_out;

    char* ws = (char*)d_ws;
    ushort_t* xb    = (ushort_t*)(ws);
    ushort_t* Wqkvb = (ushort_t*)(ws + ((size_t)8  << 20));
    ushort_t* Wpb   = (ushort_t*)(ws + ((size_t)14 << 20));
    ushort_t* qb    = (ushort_t*)(ws + ((size_t)16 << 20));
    ushort_t* kbuf  = (ushort_t*)(ws + ((size_t)24 << 20));
    ushort_t* vtb   = (ushort_t*)(ws + ((size_t)40 << 20));
    ushort_t* attno = xb;

    cast_kernel<<<8192, 256, 0, stream>>>(x, Wq, Wk, Wv, Wp, xb, Wqkvb, Wpb);

    dim3 g0(4096 / BM, 3072 / 128);
    gemm_bt<128, 0><<<g0, 256, 0, stream>>>(xb, Wqkvb, 4096, 3072, 1024,
                                            qb, kbuf, vtb, nullptr, nullptr);

    attn_kernel<<<2048, 64, 0, stream>>>(qb, kbuf, vtb, attno);

    dim3 g1(4096 / BM, 1024 / 128);
    gemm_bt<128, 1><<<g1, 256, 0, stream>>>(attno, Wpb, 4096, 1024, 1024,
                                            nullptr, nullptr, nullptr, out, bp);
}

// Round 8
// 186.201 us; speedup vs baseline: 1.2618x; 1.2618x over previous
//
#include <hip/hip_runtime.h>
#include <stdint.h>

typedef unsigned short ushort_t;
typedef __attribute__((ext_vector_type(8))) __bf16 bf16x8;
typedef __attribute__((ext_vector_type(4))) float floatx4;

__device__ __forceinline__ ushort_t f2bf(float f) {
    uint32_t u = __builtin_bit_cast(uint32_t, f);
    u += 0x7fffu + ((u >> 16) & 1u);
    return (ushort_t)(u >> 16);
}

// async 16B global->LDS (deposit at ldsbase + lane*16; ldsbase wave-uniform)
typedef __attribute__((address_space(1))) const void glb_void;
typedef __attribute__((address_space(3))) void lds_void;
__device__ __forceinline__ void gld16(const void* g, void* l) {
    __builtin_amdgcn_global_load_lds((glb_void*)g, (lds_void*)l, 16, 0, 0);
}

// Q pre-scale: dh^-0.5 * log2(e) so attention softmax runs in exp2 domain.
#define QSCALE 0.18033688011112042f

// ---------------- cast: fp32 -> bf16 ----------------
__global__ void cast_kernel(const float* __restrict__ x,
                            const float* __restrict__ Wq, const float* __restrict__ Wk,
                            const float* __restrict__ Wv, const float* __restrict__ Wp,
                            ushort_t* __restrict__ xb, ushort_t* __restrict__ Wqkvb,
                            ushort_t* __restrict__ Wpb)
{
    const int64_t NX = 4194304, NW = 1048576;
    int64_t i4 = ((int64_t)blockIdx.x * blockDim.x + threadIdx.x) * 4;
    const float* src; ushort_t* dst; int64_t off;
    if (i4 < NX)            { src = x;  dst = xb;          off = i4; }
    else if (i4 < NX+NW)    { src = Wq; dst = Wqkvb;       off = i4 - NX; }
    else if (i4 < NX+2*NW)  { src = Wk; dst = Wqkvb + NW;  off = i4 - NX - NW; }
    else if (i4 < NX+3*NW)  { src = Wv; dst = Wqkvb + 2*NW;off = i4 - NX - 2*NW; }
    else                    { src = Wp; dst = Wpb;         off = i4 - NX - 3*NW; }
    float4 v = *(const float4*)(src + off);
    ushort4 o;
    o.x = f2bf(v.x); o.y = f2bf(v.y); o.z = f2bf(v.z); o.w = f2bf(v.w);
    *(ushort4*)(dst + off) = o;
}

// ---------------- bf16 GEMM: D = A @ B^T  (global_load_lds staging) ----------------
// MODE 0 (BN_=128): scatter Q,K -> [bh][s][d] (Q pre-scaled), V -> [bh][d][s]
// MODE 1: fp32 out = D + bias
#define BM 128
#define BK 32

template<int BN_, int MODE>
__global__ __launch_bounds__(256, 3)
void gemm_bt(const ushort_t* __restrict__ A, const ushort_t* __restrict__ Bmat,
             int M, int N, int K,
             ushort_t* __restrict__ qb, ushort_t* __restrict__ kb, ushort_t* __restrict__ vtb,
             float* __restrict__ outf, const float* __restrict__ bias)
{
    constexpr int NB_B = BN_ * BK / 512;
    constexpr int NT   = BN_ / 32;
    constexpr int PER_W = (8 + NB_B) / 4;
    __shared__ ushort_t As[BM * BK];
    __shared__ ushort_t Bs[BN_ * BK];
    const int tid  = threadIdx.x;
    const int lane = tid & 63;
    const int wave = tid >> 6;
    const int m0 = blockIdx.x * BM;
    const int n0 = blockIdx.y * BN_;
    const int wrow = (wave >> 1) * 64;
    const int wcol = (wave & 1) * (BN_ / 2);
    const int q_ = lane >> 4;
    const int ml = lane & 15;

    floatx4 acc[4][NT];
    for (int i = 0; i < 4; i++) for (int j = 0; j < NT; j++) acc[i][j] = floatx4{0.f,0.f,0.f,0.f};

    const int row_l = lane >> 2;
    const int col_l = (lane & 3) * 8;
    const ushort_t* gptr[PER_W]; ushort_t* lptr[PER_W];
    for (int i = 0; i < PER_W; i++) {
        int id = wave * PER_W + i;
        if (id < 8) {
            gptr[i] = A + (int64_t)(m0 + id*16 + row_l) * K + col_l;
            lptr[i] = As + id * 512;
        } else {
            int j = id - 8;
            gptr[i] = Bmat + (int64_t)(n0 + j*16 + row_l) * K + col_l;
            lptr[i] = Bs + j * 512;
        }
    }

    for (int k0 = 0; k0 < K; k0 += BK) {
        __syncthreads();
        for (int i = 0; i < PER_W; i++) gld16(gptr[i] + k0, lptr[i]);
        __syncthreads();
        bf16x8 af[4], bf[NT];
        for (int mt = 0; mt < 4; mt++)
            af[mt] = *(const bf16x8*)(As + (wrow + mt*16 + ml) * BK + q_*8);
        for (int nt = 0; nt < NT; nt++)
            bf[nt] = *(const bf16x8*)(Bs + (wcol + nt*16 + ml) * BK + q_*8);
        for (int mt = 0; mt < 4; mt++)
            for (int nt = 0; nt < NT; nt++)
                acc[mt][nt] = __builtin_amdgcn_mfma_f32_16x16x32_bf16(af[mt], bf[nt], acc[mt][nt], 0, 0, 0);
    }

    if constexpr (MODE == 0) {
        for (int mt = 0; mt < 4; mt++) for (int nt = 0; nt < NT; nt++) {
            floatx4 v = acc[mt][nt];
            int col = n0 + wcol + nt*16 + ml;
            int which = col >> 10;
            int nn = col & 1023;
            int h = nn >> 6, d = nn & 63;
            if (which < 2) {
                ushort_t* dst = (which == 0) ? qb : kb;
                float sc = (which == 0) ? QSCALE : 1.0f;
                for (int r = 0; r < 4; r++) {
                    int rowg = m0 + wrow + mt*16 + q_*4 + r;
                    int b = rowg >> 11, s = rowg & 2047;
                    dst[(((int64_t)(b*16 + h) * 2048 + s) << 6) + d] = f2bf(v[r] * sc);
                }
            } else {
                int rowg0 = m0 + wrow + mt*16 + q_*4;
                int b = rowg0 >> 11, sbase = rowg0 & 2047;
                ushort4 o;
                o.x = f2bf(v[0]); o.y = f2bf(v[1]); o.z = f2bf(v[2]); o.w = f2bf(v[3]);
                *(ushort4*)(vtb + (((int64_t)(b*16 + h) * 64 + d) << 11) + sbase) = o;
            }
        }
    } else {
        for (int mt = 0; mt < 4; mt++) for (int nt = 0; nt < NT; nt++) {
            floatx4 v = acc[mt][nt];
            int col = n0 + wcol + nt*16 + ml;
            float bv = bias[col];
            for (int r = 0; r < 4; r++) {
                int rowg = m0 + wrow + mt*16 + q_*4 + r;
                outf[(int64_t)rowg * N + col] = v[r] + bv;
            }
        }
    }
}

// ---------------- fused masked flash attention, operand-swapped MFMA ----------------
// Computes S^T = K·Q^T and O^T = V^T·P^T. K is staged into LDS with key-permuted
// rows (key = 8*(m>>2)+(m&3)+4t) so each S^T C-tile IS the P^T B-fragment after
// exp2 — no P LDS round-trip, no cross-lane ops. 2 waves/block, 32 q-rows/wave.
__global__ __launch_bounds__(128, 2)
void attn_kernel(const ushort_t* __restrict__ Q, const ushort_t* __restrict__ Kb,
                 const ushort_t* __restrict__ Vt, ushort_t* __restrict__ Out)
{
    __shared__ ushort_t Kl[8192];   // 16KB: 16 cells of 1KB, key-permuted rows
    __shared__ ushort_t Vl[8192];   // 16KB: 16 cells of 1KB, lane-linear

    int bi = blockIdx.x;            // 1024 blocks
    int xcd = bi & 7;
    int sl  = bi >> 3;
    int bh  = xcd + 8 * (sl & 3);
    int rest = sl >> 2;             // 0..31
    int qv = 7 - (rest >> 2);       // heavy views first
    int qt = rest & 3;
    int b = bh >> 4, h = bh & 15;
    int tid = threadIdx.x;
    int wave = tid >> 6, lane = tid & 63;
    int q_ = lane >> 4, ml = lane & 15;
    int s0 = qv*256 + qt*64 + wave*32;

    const ushort_t* Kbh = Kb + ((int64_t)bh << 17);
    const ushort_t* Vbh = Vt + ((int64_t)bh << 17);

    // Q as B-operand: lane holds Q[s0+qf*16+ml][32*hh + 8*q_ .. +7]  (unchanged layout)
    bf16x8 bq[2][2];
    for (int qf = 0; qf < 2; qf++)
        for (int hh = 0; hh < 2; hh++)
            bq[qf][hh] = *(const bf16x8*)(Q + (((int64_t)bh*2048 + s0 + qf*16 + ml) << 6)
                                          + hh*32 + q_*8);

    floatx4 o_acc[2][4];
    for (int qf = 0; qf < 2; qf++) for (int i = 0; i < 4; i++) o_acc[qf][i] = floatx4{0.f,0.f,0.f,0.f};
    float lsum[2] = {0.f, 0.f};     // per-lane: all of this lane's p belong to qrow=ml

    int views[8]; int nviews;
    if      (qv == 0) { views[0] = 1; nviews = 1; }
    else if (qv == 1) { views[0] = 0; nviews = 1; }
    else { nviews = qv + 1; for (int i = 0; i < nviews; i++) views[i] = i; }

    // staging lane decomposition (per wave)
    int m_ = lane & 15, q5 = lane >> 4;
    int kperm = (m_ >> 2)*8 + (m_ & 3);       // key-permuted row within 32-key window

    for (int vi = 0; vi < nviews; vi++) {
        int kb0 = views[vi] * 256;
        for (int ck = 0; ck < 2; ck++) {
            int koff = kb0 + ck * 128;

            __syncthreads();   // prior chunk's LDS reads complete
            if (wave == 0) {
                // K cells: c = w*4 + t*2 + hh ; row = koff+32w+4t+kperm, col = 32hh+8q5
                #pragma unroll
                for (int id = 0; id < 16; id++) {
                    int w = id >> 2, t = (id >> 1) & 1, hh = id & 1;
                    const ushort_t* g = Kbh
                        + (((int64_t)(koff + w*32 + t*4 + kperm)) << 6) + hh*32 + q5*8;
                    gld16(g, Kl + id*512);
                }
            } else {
                // V cells: c = w*4 + dt ; Vt row dt*16+m_, keys koff+32w+8q5..
                #pragma unroll
                for (int id = 0; id < 16; id++) {
                    int w = id >> 2, dt = id & 3;
                    const ushort_t* g = Vbh
                        + ((int64_t)(dt*16 + m_) << 11) + koff + w*32 + q5*8;
                    gld16(g, Vl + id*512);
                }
            }
            __syncthreads();   // loads landed

            #pragma unroll
            for (int w = 0; w < 4; w++) {
                // ---- S^T tiles X(t=0), Y(t=1) over this 32-key window ----
                floatx4 st[2][2];   // [t][qf]
                #pragma unroll
                for (int t = 0; t < 2; t++) {
                    bf16x8 k0 = *(const bf16x8*)(Kl + (w*4 + t*2 + 0)*512 + lane*8);
                    bf16x8 k1 = *(const bf16x8*)(Kl + (w*4 + t*2 + 1)*512 + lane*8);
                    #pragma unroll
                    for (int qf = 0; qf < 2; qf++) {
                        floatx4 cz = floatx4{0.f,0.f,0.f,0.f};
                        cz = __builtin_amdgcn_mfma_f32_16x16x32_bf16(k0, bq[qf][0], cz, 0, 0, 0);
                        cz = __builtin_amdgcn_mfma_f32_16x16x32_bf16(k1, bq[qf][1], cz, 0, 0, 0);
                        st[t][qf] = cz;
                    }
                }
                // ---- p = exp2(s); C-regs ARE the P^T B-frag (X regs = j<4, Y = j>=4) ----
                bf16x8 pb[2];
                #pragma unroll
                for (int qf = 0; qf < 2; qf++) {
                    union { ushort_t u[8]; bf16x8 v; } pu;
                    #pragma unroll
                    for (int t = 0; t < 2; t++)
                        #pragma unroll
                        for (int r = 0; r < 4; r++) {
                            float p = __builtin_amdgcn_exp2f(st[t][qf][r]);
                            lsum[qf] += p;
                            pu.u[t*4 + r] = f2bf(p);
                        }
                    pb[qf] = pu.v;
                }
                // ---- O^T += V^T · P^T ----
                #pragma unroll
                for (int dt = 0; dt < 4; dt++) {
                    bf16x8 vf = *(const bf16x8*)(Vl + (w*4 + dt)*512 + lane*8);
                    #pragma unroll
                    for (int qf = 0; qf < 2; qf++)
                        o_acc[qf][dt] = __builtin_amdgcn_mfma_f32_16x16x32_bf16(vf, pb[qf], o_acc[qf][dt], 0, 0, 0);
                }
            }
        }
    }

    // reduce lsum across the 4 lane groups (same ml, different q_)
    for (int off = 16; off < 64; off <<= 1)
        for (int qf = 0; qf < 2; qf++)
            lsum[qf] += __shfl_xor(lsum[qf], off);

    // epilogue: O^T C-layout: lane holds O[qrow=ml][d = dt*16 + 4q_ + r]
    for (int qf = 0; qf < 2; qf++) {
        float inv = 1.0f / lsum[qf];
        int sr = s0 + qf*16 + ml;
        for (int dt = 0; dt < 4; dt++) {
            ushort4 o;
            o.x = f2bf(o_acc[qf][dt][0] * inv);
            o.y = f2bf(o_acc[qf][dt][1] * inv);
            o.z = f2bf(o_acc[qf][dt][2] * inv);
            o.w = f2bf(o_acc[qf][dt][3] * inv);
            *(ushort4*)(Out + ((int64_t)b*2048 + sr) * 1024 + h*64 + dt*16 + q_*4) = o;
        }
    }
}

extern "C" void kernel_launch(void* const* d_in, const int* in_sizes, int n_in,
                              void* d_out, int out_size, void* d_ws, size_t ws_size,
                              hipStream_t stream) {
    const float* x  = (const float*)d_in[0];
    const float* Wq = (const float*)d_in[1];
    const float* Wk = (const float*)d_in[2];
    const float* Wv = (const float*)d_in[3];
    const float* Wp = (const float*)d_in[4];
    const float* bp = (const float*)d_in[5];
    float* out = (float*)d_out;

    char* ws = (char*)d_ws;
    ushort_t* xb    = (ushort_t*)(ws);
    ushort_t* Wqkvb = (ushort_t*)(ws + ((size_t)8  << 20));
    ushort_t* Wpb   = (ushort_t*)(ws + ((size_t)14 << 20));
    ushort_t* qb    = (ushort_t*)(ws + ((size_t)16 << 20));
    ushort_t* kbuf  = (ushort_t*)(ws + ((size_t)24 << 20));
    ushort_t* vtb   = (ushort_t*)(ws + ((size_t)40 << 20));
    ushort_t* attno = xb;

    cast_kernel<<<8192, 256, 0, stream>>>(x, Wq, Wk, Wv, Wp, xb, Wqkvb, Wpb);

    dim3 g0(4096 / BM, 3072 / 128);
    gemm_bt<128, 0><<<g0, 256, 0, stream>>>(xb, Wqkvb, 4096, 3072, 1024,
                                            qb, kbuf, vtb, nullptr, nullptr);

    attn_kernel<<<1024, 128, 0, stream>>>(qb, kbuf, vtb, attno);

    dim3 g1(4096 / BM, 1024 / 64);
    gemm_bt<64, 1><<<g1, 256, 0, stream>>>(attno, Wpb, 4096, 1024, 1024,
                                           nullptr, nullptr, nullptr, out, bp);
}